// Round 7
// baseline (82.148 us; speedup 1.0000x reference)
//
#include <hip/hip_runtime.h>

// RoI crop_and_resize (tf.image.crop_and_resize, bilinear), single image.
// feature: [1,50,50,1024] f32; rois: [512,4] f32; img_size: [2] i32.
// Output: [512,14,14,1024] f32.
//
// R6: burst-size restructure. Slice = 256 channels = 64 f32x4 quads = ONE
// wave's 64 lanes -> every tap load and every output store is a single 1KB
// contiguous per-wave burst (R5 had 256B chunks; memset sustains 6.8 TB/s
// with 1KB/wave, we were at 5.1). Block = 448 thr = 7 waves = 7 j-columns,
// 2 j-passes (14 = 2*7, zero idle lanes). Bilinear weights/addresses are
// wave-uniform -> scalarized by the compiler.
// XCD decode: s = bid&3, n = bid>>2 -> XCD x only ever reads slice x&3
// (50*50*256*4 = 2.56MB, L2-resident; cross-RoI re-reads are L2 hits).
// NT stores keep the 411MB streaming output from thrashing that slice.

#define FH 50
#define FW 50
#define FC 1024
#define PH 14
#define PW 14
#define CS 256                // channels per slice
#define NSL (FC / CS)         // 4 slices
#define QS (CS / 4)           // 64 f32x4 quads per slice = 1 wave

typedef float f32x4 __attribute__((ext_vector_type(4)));

__global__ __launch_bounds__(448) void roi_crop_resize_kernel(
    const float* __restrict__ feat,
    const float* __restrict__ rois,
    const int* __restrict__ img_size,
    float* __restrict__ out)
{
    int bid = blockIdx.x;
    int n = bid >> 2;          // RoI index
    int s = bid & (NSL - 1);   // channel slice; XCD = bid&7 -> slice bid&3
    int t = threadIdx.x;
    int q = t & 63;            // quad within slice (64 x f32x4 = 256 ch) = lane
    int g = t >> 6;            // wave id = j-group, 0..6

    float hs = (float)img_size[0];
    float ws = (float)img_size[1];
    float by1 = rois[n * 4 + 0] / hs;
    float bx1 = rois[n * 4 + 1] / ws;
    float by2 = rois[n * 4 + 2] / hs;
    float bx2 = rois[n * 4 + 3] / ws;

    float ybase = by1 * (float)(FH - 1);
    float dy    = (by2 - by1) * (float)(FH - 1) * (1.0f / (float)(PH - 1));
    float xbase = bx1 * (float)(FW - 1);
    float dxs   = (bx2 - bx1) * (float)(FW - 1) * (1.0f / (float)(PW - 1));

    // per-pass x interpolation (wave-uniform: depends only on g, jc)
    int   x0[2], x1[2];
    float wx[2];
    #pragma unroll
    for (int jc = 0; jc < 2; ++jc) {
        int j = jc * 7 + g;
        float xs  = xbase + (float)j * dxs;
        float x0f = floorf(xs);
        wx[jc] = xs - x0f;
        x0[jc] = (int)fminf(fmaxf(x0f,        0.0f), (float)(FW - 1));
        x1[jc] = (int)fminf(fmaxf(x0f + 1.0f, 0.0f), (float)(FW - 1));
    }

    const f32x4* fq = (const f32x4*)feat;
    int sq = s * QS + q;                       // quad index within a pixel
    f32x4* ob = (f32x4*)out + (size_t)(n * (PH * PW)) * (FC / 4) + sq;

    #pragma unroll
    for (int i = 0; i < PH; ++i) {
        float ysf = ybase + (float)i * dy;
        float y0f = floorf(ysf);
        float wy  = ysf - y0f;
        int r0 = (int)fminf(fmaxf(y0f,        0.0f), (float)(FH - 1));
        int r1 = (int)fminf(fmaxf(y0f + 1.0f, 0.0f), (float)(FH - 1));
        float omwy = 1.0f - wy;
        int bT = (r0 * FW) * (FC / 4) + sq;
        int bB = (r1 * FW) * (FC / 4) + sq;

        #pragma unroll
        for (int jc = 0; jc < 2; ++jc) {
            int j = jc * 7 + g;
            f32x4 a = fq[bT + x0[jc] * (FC / 4)];
            f32x4 b = fq[bT + x1[jc] * (FC / 4)];
            f32x4 c = fq[bB + x0[jc] * (FC / 4)];
            f32x4 d = fq[bB + x1[jc] * (FC / 4)];

            float w  = wx[jc];
            float ow = 1.0f - w;
            // reference ordering: top = a*(1-wx)+b*wx; bot = c*(1-wx)+d*wx;
            // out = top*(1-wy) + bot*wy
            f32x4 res = (a * ow + b * w) * omwy + (c * ow + d * w) * wy;

            __builtin_nontemporal_store(res, ob + (i * PW + j) * (FC / 4));
        }
    }
}

extern "C" void kernel_launch(void* const* d_in, const int* in_sizes, int n_in,
                              void* d_out, int out_size, void* d_ws, size_t ws_size,
                              hipStream_t stream) {
    const float* feat     = (const float*)d_in[0];
    const float* rois     = (const float*)d_in[1];
    const int*   img_size = (const int*)d_in[2];
    float* out = (float*)d_out;

    int n_rois = in_sizes[1] / 4;            // 512
    int grid   = n_rois * NSL;               // 2048 blocks

    roi_crop_resize_kernel<<<grid, 448, 0, stream>>>(feat, rois, img_size, out);
}